// Round 1
// 745.525 us; speedup vs baseline: 2.8652x; 2.8652x over previous
//
#include <hip/hip_runtime.h>

// ---------------------------------------------------------------------------
// MultiHeadAttention: out = softmax(mask( (xWq)(xWk)^T / sqrt(64) )) (xWv) Wo
// B=4 S=2048 D=1024 H=16 Dh=64. Inputs fp32, mask int32, output fp32.
//
// R12: replace the four pure-VALU fp32 GEMMs (4 x 480us = 90% of runtime,
// MfmaUtil=0) with split-bf16 3-pass MFMA GEMMs:
//   x = x_hi + x_lo (bf16 each);  x.w ~= xh.wh + xh.wl + xl.wh  (fp32 acc)
// -> fp32-level accuracy (~2^-18 rel) at ~1/3 of bf16 MFMA rate, i.e. an
// effective ~10x over the 36 TF VALU GEMM. Weights pre-split in the
// transpose kernel; activations split on the fly during LDS staging.
// LDS tiles XOR-swizzled (byte ^= (row&7)<<4, applied on BOTH write and
// read) for conflict-free ds_read_b128 fragment loads.
// Attention kernel unchanged (HW-verified in R11).
// ---------------------------------------------------------------------------

typedef unsigned short u16;
typedef __attribute__((ext_vector_type(8))) short short8;
typedef __attribute__((ext_vector_type(8))) unsigned short u16x8;
typedef __attribute__((ext_vector_type(4))) float floatx4;

__device__ u16 g_Bth[4][1024 * 1024];  // WqT,WkT,WvT,WoT hi bf16
__device__ u16 g_Btl[4][1024 * 1024];  // lo bf16
__device__ u16 g_Qh[8192 * 1024];      // bf16 Q projection
__device__ u16 g_Kh[8192 * 1024];      // bf16 K projection
__device__ u16 g_Vh[8192 * 1024];      // bf16 V projection
__device__ float g_O[8192 * 1024];     // fp32 attention output
__device__ int g_is_bf16;              // guard: input float dtype

__device__ __forceinline__ float bf2f(u16 u) {
  union { unsigned int i; float f; } v;
  v.i = ((unsigned int)u) << 16;
  return v.f;
}
__device__ __forceinline__ u16 f2bf(float f) {  // round-to-nearest-even
  union { float f; unsigned int i; } v;
  v.f = f;
  unsigned int r = v.i + 0x7fffu + ((v.i >> 16) & 1u);
  return (u16)(r >> 16);
}

// float-dtype guard (R6-validated): fp32 expected (g_is_bf16=0)
__global__ void detect_kernel(const u16* __restrict__ q) {
  if (threadIdx.x == 0) {
    int cnt = 0;
    for (int i = 0; i < 256; ++i) {
      const u16 v = q[i];
      const int e = (v >> 7) & 0xFF;
      cnt += ((e >= 100 && e <= 135) || ((v & 0x7FFF) == 0)) ? 1 : 0;
    }
    g_is_bf16 = (cnt >= 205) ? 1 : 0;
  }
}

__device__ __forceinline__ float load_in(const void* p, size_t i) {
  return g_is_bf16 ? bf2f(((const u16*)p)[i]) : ((const float*)p)[i];
}

// LDS XOR swizzle: byte offset of (row, colbyte) in a [128][64B] bf16 tile.
// Bijective (mask bits 4..6 from row bits 0..2); keeps 16B alignment.
// Frag reads (rows=base+lanelo, col=quad*16) land 8 lanes per 16B slot ->
// conflict-free b128. Must be applied identically on write and read.
__device__ __forceinline__ int swz(int row, int cb) {
  return ((row << 6) + cb) ^ ((row & 7) << 4);
}

// ---------------------------------------------------------------------------
// 1024x1024 transpose -> split bf16 hi/lo; out = g_Bth[wo], g_Btl[wo]
// ---------------------------------------------------------------------------
__global__ void wtrans_kernel(const void* __restrict__ in, int wo) {
  __shared__ float tile[32][33];
  const int tx = threadIdx.x, ty = threadIdx.y;
  const int n0 = blockIdx.x * 32, k0 = blockIdx.y * 32;
  tile[ty][tx] = load_in(in, (size_t)(k0 + ty) * 1024 + n0 + tx);
  __syncthreads();
  const float v = tile[tx][ty];
  const u16 h = f2bf(v);
  const u16 l = f2bf(v - bf2f(h));
  const size_t o = (size_t)(n0 + ty) * 1024 + k0 + tx;
  g_Bth[wo][o] = h;
  g_Btl[wo][o] = l;
}

// ---------------------------------------------------------------------------
// Split-bf16 MFMA GEMM: C[8192][1024] = A[8192][1024] x W + bias, W^T given
// pre-split in g_Bth/g_Btl[bt] ([n][k] layout, k contiguous).
// 128x128 tile, BK=32, 256 threads = 4 waves (2x2), 4x4 16x16x32 frags/wave.
// 3 MFMA passes per frag pair: Ah.Bh + Ah.Bl + Al.Bh (fp32 accumulate).
// a_sel: 0 = Aptr (external fp32 input, split on the fly), 1 = g_O (fp32).
// c_sel: 0/1/2 -> bf16 stores to g_Qh/g_Kh/g_Vh; 3 -> fp32 store to Cptr.
// Fragment layouts (HW-verified via attn kernel): A: m=lane&15, k=quad*8+j;
// B: n=lane&15, k=quad*8+j; C/D: col(n)=lane&15, row(m)=quad*4+reg.
// ---------------------------------------------------------------------------
__global__ __launch_bounds__(256) void gemm_mfma_kernel(
    const void* __restrict__ Aptr, int a_sel, int bt,
    const void* __restrict__ bias, float* __restrict__ Cptr, int c_sel) {
  constexpr int K = 1024, N = 1024;
  __shared__ __align__(16) u16 Ahs[128 * 32];
  __shared__ __align__(16) u16 Als[128 * 32];
  __shared__ __align__(16) u16 Bhs[128 * 32];
  __shared__ __align__(16) u16 Bls[128 * 32];

  const u16* Bth = g_Bth[bt];
  const u16* Btl = g_Btl[bt];
  u16* Ch = (c_sel == 0) ? g_Qh : (c_sel == 1) ? g_Kh : g_Vh;

  const int t = threadIdx.x;
  const int lane = t & 63;
  const int lanelo = lane & 15;
  const int quad = lane >> 4;
  const int wave = t >> 6;
  const int wr = wave >> 1, wc = wave & 1;

  const int bm = blockIdx.x * 128;
  const int bn = blockIdx.y * 128;

  const int sr = t >> 1;        // staging row 0..127
  const int sc = (t & 1) * 16;  // staging col (elements), 16 elems/thread row-half

  const int bf = g_is_bf16;

  floatx4 acc[4][4];
#pragma unroll
  for (int i = 0; i < 4; ++i)
#pragma unroll
    for (int j = 0; j < 4; ++j) acc[i][j] = (floatx4)(0.f);

  for (int k0 = 0; k0 < K; k0 += 32) {
    // ---- global loads for this K-step (issued before barrier; latency
    //      overlaps the other resident block's MFMA phase) ----
    float af[16];
    {
      const size_t ga = (size_t)(bm + sr) * K + k0 + sc;
      if (a_sel) {
#pragma unroll
        for (int i = 0; i < 4; ++i) {
          const float4 v = *(const float4*)(g_O + ga + i * 4);
          af[i * 4 + 0] = v.x; af[i * 4 + 1] = v.y;
          af[i * 4 + 2] = v.z; af[i * 4 + 3] = v.w;
        }
      } else if (!bf) {
#pragma unroll
        for (int i = 0; i < 4; ++i) {
          const float4 v = *(const float4*)((const float*)Aptr + ga + i * 4);
          af[i * 4 + 0] = v.x; af[i * 4 + 1] = v.y;
          af[i * 4 + 2] = v.z; af[i * 4 + 3] = v.w;
        }
      } else {
#pragma unroll
        for (int i = 0; i < 2; ++i) {
          const u16x8 v = *(const u16x8*)((const u16*)Aptr + ga + i * 8);
#pragma unroll
          for (int j = 0; j < 8; ++j) af[i * 8 + j] = bf2f(v[j]);
        }
      }
    }
    u16x8 bhv[2], blv[2];
    {
      const size_t gb = (size_t)(bn + sr) * K + k0 + sc;
      bhv[0] = *(const u16x8*)(Bth + gb);
      bhv[1] = *(const u16x8*)(Bth + gb + 8);
      blv[0] = *(const u16x8*)(Btl + gb);
      blv[1] = *(const u16x8*)(Btl + gb + 8);
    }

    __syncthreads();  // previous iteration's LDS reads complete

    // ---- split A hi/lo + swizzled LDS writes (ds_write_b128) ----
    u16x8 ahv[2], alv[2];
#pragma unroll
    for (int i = 0; i < 2; ++i) {
#pragma unroll
      for (int j = 0; j < 8; ++j) {
        const float v = af[i * 8 + j];
        const u16 h = f2bf(v);
        ahv[i][j] = h;
        alv[i][j] = f2bf(v - bf2f(h));
      }
    }
#pragma unroll
    for (int i = 0; i < 2; ++i) {
      const int cb = sc * 2 + i * 16;  // byte col within 64B row
      const int o = swz(sr, cb) >> 1;
      *(u16x8*)&Ahs[o] = ahv[i];
      *(u16x8*)&Als[o] = alv[i];
      *(u16x8*)&Bhs[o] = bhv[i];
      *(u16x8*)&Bls[o] = blv[i];
    }

    __syncthreads();  // writes visible

    // ---- fragment loads (swizzled ds_read_b128) + 48 MFMAs ----
    short8 a_h[4], a_l[4], b_h[4], b_l[4];
#pragma unroll
    for (int mi = 0; mi < 4; ++mi) {
      const int row = wr * 64 + mi * 16 + lanelo;
      const int o = swz(row, quad * 16) >> 1;
      a_h[mi] = *(const short8*)&Ahs[o];
      a_l[mi] = *(const short8*)&Als[o];
    }
#pragma unroll
    for (int ni = 0; ni < 4; ++ni) {
      const int row = wc * 64 + ni * 16 + lanelo;
      const int o = swz(row, quad * 16) >> 1;
      b_h[ni] = *(const short8*)&Bhs[o];
      b_l[ni] = *(const short8*)&Bls[o];
    }
#pragma unroll
    for (int mi = 0; mi < 4; ++mi)
#pragma unroll
      for (int ni = 0; ni < 4; ++ni) {
        acc[mi][ni] = __builtin_amdgcn_mfma_f32_16x16x32_bf16(
            a_h[mi], b_h[ni], acc[mi][ni], 0, 0, 0);
        acc[mi][ni] = __builtin_amdgcn_mfma_f32_16x16x32_bf16(
            a_h[mi], b_l[ni], acc[mi][ni], 0, 0, 0);
        acc[mi][ni] = __builtin_amdgcn_mfma_f32_16x16x32_bf16(
            a_l[mi], b_h[ni], acc[mi][ni], 0, 0, 0);
      }
  }

  // ---- epilogue: + bias, store ----
#pragma unroll
  for (int ni = 0; ni < 4; ++ni) {
    const int col = bn + wc * 64 + ni * 16 + lanelo;
    const float bv = bf ? bf2f(((const u16*)bias)[col])
                        : ((const float*)bias)[col];
#pragma unroll
    for (int mi = 0; mi < 4; ++mi) {
#pragma unroll
      for (int rg = 0; rg < 4; ++rg) {
        const int row = bm + wr * 64 + mi * 16 + quad * 4 + rg;
        const float v = acc[mi][ni][rg] + bv;
        if (c_sel == 3)
          Cptr[(size_t)row * N + col] = v;
        else
          Ch[(size_t)row * N + col] = f2bf(v);
      }
    }
  }
}

// ---------------------------------------------------------------------------
// MFMA flash attention: block = (64-q-tile, h, b), 256 threads (4 waves).
// Reads bf16 g_Qh/g_Kh/g_Vh + int32 mask; writes fp32 O to g_O.
// (unchanged from R11 — HW-verified)
// ---------------------------------------------------------------------------
__global__ __launch_bounds__(256) void attn_mfma_kernel(const int* __restrict__ mask) {
  constexpr int S = 2048, D = 1024;
  constexpr int LD = 72;
  __shared__ __align__(16) u16 q_s[64 * LD];
  __shared__ __align__(16) u16 k_s[64 * LD];
  __shared__ __align__(16) u16 vt_s[64 * LD];  // vT[d][j]
  __shared__ __align__(16) u16 p_s[64 * LD];   // per-wave 16-row strips

  const int t = threadIdx.x;
  const int lane = t & 63;
  const int lanelo = lane & 15;
  const int quad = lane >> 4;
  const int wave = t >> 6;

  const int q0 = blockIdx.x * 64;
  const int h = blockIdx.y;
  const int b = blockIdx.z;
  const size_t bh = (size_t)b * S * D + (size_t)h * 64;

  // stage Q tile [64 x 64]: row j = t&63, col chunks cc = (wave+4i)*8
  {
    const int j = t & 63;
#pragma unroll
    for (int i = 0; i < 2; ++i) {
      const int cc = (wave + i * 4) * 8;
      *(u16x8*)&q_s[j * LD + cc] =
          *(const u16x8*)(g_Qh + bh + (size_t)(q0 + j) * D + cc);
    }
  }

  floatx4 o_acc[4];
#pragma unroll
  for (int ni = 0; ni < 4; ++ni) o_acc[ni] = (floatx4)(0.f);
  float m_r[4] = {-1e30f, -1e30f, -1e30f, -1e30f};
  float l_r[4] = {0.f, 0.f, 0.f, 0.f};

  for (int kt = 0; kt < S / 64; ++kt) {
    const int j0 = kt * 64;
    __syncthreads();  // prev-iter LDS reads done (and q_s visible on kt=0)
    {
      const int j = t & 63;
#pragma unroll
      for (int i = 0; i < 2; ++i) {
        const int cc = (wave + i * 4) * 8;
        *(u16x8*)&k_s[j * LD + cc] =
            *(const u16x8*)(g_Kh + bh + (size_t)(j0 + j) * D + cc);
        const u16x8 vv = *(const u16x8*)(g_Vh + bh + (size_t)(j0 + j) * D + cc);
#pragma unroll
        for (int u = 0; u < 8; ++u) vt_s[(cc + u) * LD + j] = vv[u];  // transpose
      }
    }
    __syncthreads();

    // scores [16q x 64j] per wave
    floatx4 sacc[4];
#pragma unroll
    for (int ni = 0; ni < 4; ++ni) sacc[ni] = (floatx4)(0.f);
#pragma unroll
    for (int kk = 0; kk < 2; ++kk) {
      const short8 a =
          *(const short8*)&q_s[(wave * 16 + lanelo) * LD + kk * 32 + quad * 8];
#pragma unroll
      for (int ni = 0; ni < 4; ++ni) {
        const short8 bb =
            *(const short8*)&k_s[(ni * 16 + lanelo) * LD + kk * 32 + quad * 8];
        sacc[ni] = __builtin_amdgcn_mfma_f32_16x16x32_bf16(a, bb, sacc[ni], 0, 0, 0);
      }
    }

    // mask + scale; element (ni,r): row=quad*4+r, col=ni*16+lanelo
    float sc[4][4];
    const int gi0 = q0 + wave * 16 + quad * 4;
    const int* mb = mask + (size_t)b * S * S + j0 + lanelo;
#pragma unroll
    for (int r = 0; r < 4; ++r) {
      const int* mp = mb + (size_t)(gi0 + r) * S;
#pragma unroll
      for (int ni = 0; ni < 4; ++ni)
        sc[ni][r] = (mp[ni * 16] != 0) ? sacc[ni][r] * 0.125f : -1e9f;
    }

    // online softmax per row r; reduce across the quad's 16 lanes
#pragma unroll
    for (int r = 0; r < 4; ++r) {
      float mloc = fmaxf(fmaxf(sc[0][r], sc[1][r]), fmaxf(sc[2][r], sc[3][r]));
#pragma unroll
      for (int off = 1; off < 16; off <<= 1)
        mloc = fmaxf(mloc, __shfl_xor(mloc, off, 16));
      const float m_new = fmaxf(m_r[r], mloc);
      const float alpha = __expf(m_r[r] - m_new);
      m_r[r] = m_new;
      float ps = 0.f;
#pragma unroll
      for (int ni = 0; ni < 4; ++ni) {
        const float p = __expf(sc[ni][r] - m_new);
        ps += p;
        p_s[(wave * 16 + quad * 4 + r) * LD + ni * 16 + lanelo] = f2bf(p);
      }
#pragma unroll
      for (int off = 1; off < 16; off <<= 1) ps += __shfl_xor(ps, off, 16);
      l_r[r] = l_r[r] * alpha + ps;
#pragma unroll
      for (int ni = 0; ni < 4; ++ni) o_acc[ni][r] *= alpha;
    }

    __syncthreads();  // order cross-lane p_s writes before A-layout reads

    // O += P V
#pragma unroll
    for (int kk = 0; kk < 2; ++kk) {
      const short8 a =
          *(const short8*)&p_s[(wave * 16 + lanelo) * LD + kk * 32 + quad * 8];
#pragma unroll
      for (int ni = 0; ni < 4; ++ni) {
        const short8 bb =
            *(const short8*)&vt_s[(ni * 16 + lanelo) * LD + kk * 32 + quad * 8];
        o_acc[ni] = __builtin_amdgcn_mfma_f32_16x16x32_bf16(a, bb, o_acc[ni], 0, 0, 0);
      }
    }
  }

  // epilogue: divide by l, store fp32 O
#pragma unroll
  for (int ni = 0; ni < 4; ++ni) {
#pragma unroll
    for (int r = 0; r < 4; ++r) {
      const int row = q0 + wave * 16 + quad * 4 + r;
      g_O[bh + (size_t)row * D + ni * 16 + lanelo] = o_acc[ni][r] / l_r[r];
    }
  }
}

// ---------------------------------------------------------------------------
extern "C" void kernel_launch(void* const* d_in, const int* in_sizes, int n_in,
                              void* d_out, int out_size, void* d_ws, size_t ws_size,
                              hipStream_t stream) {
  const void* query = d_in[0];
  const void* key   = d_in[1];
  const void* value = d_in[2];
  const int* mask   = (const int*)d_in[3];
  const void* Wq = d_in[4];
  const void* bq = d_in[5];
  const void* Wk = d_in[6];
  const void* bk = d_in[7];
  const void* Wv = d_in[8];
  const void* bv = d_in[9];
  const void* Wo = d_in[10];
  const void* bo = d_in[11];

  detect_kernel<<<1, 64, 0, stream>>>((const u16*)query);

  dim3 tb(32, 32), tg(32, 32);
  wtrans_kernel<<<tg, tb, 0, stream>>>(Wq, 0);
  wtrans_kernel<<<tg, tb, 0, stream>>>(Wk, 1);
  wtrans_kernel<<<tg, tb, 0, stream>>>(Wv, 2);
  wtrans_kernel<<<tg, tb, 0, stream>>>(Wo, 3);

  dim3 gg(64, 8);  // 8192/128 x 1024/128
  gemm_mfma_kernel<<<gg, 256, 0, stream>>>(query, 0, 0, bq, nullptr, 0);
  gemm_mfma_kernel<<<gg, 256, 0, stream>>>(key,   0, 1, bk, nullptr, 1);
  gemm_mfma_kernel<<<gg, 256, 0, stream>>>(value, 0, 2, bv, nullptr, 2);

  attn_mfma_kernel<<<dim3(32, 16, 4), 256, 0, stream>>>(mask);

  gemm_mfma_kernel<<<gg, 256, 0, stream>>>(nullptr, 1, 3, bo, (float*)d_out, 3);
}

// Round 3
// 646.541 us; speedup vs baseline: 3.3039x; 1.1531x over previous
//
#include <hip/hip_runtime.h>

// ---------------------------------------------------------------------------
// MultiHeadAttention: out = softmax(mask( (xWq)(xWk)^T / sqrt(64) )) (xWv) Wo
// B=4 S=2048 D=1024 H=16 Dh=64. Inputs fp32, mask int32, output fp32.
//
// R14 == R13 resubmitted (R13 bench failed with GPUAcquisitionTimeout; no
// counters produced). Attention rework vs R12 (was 333us, MfmaUtil 9%):
//  - Q fragments hoisted to registers (invariant across K-tiles)
//  - 8-wave blocks (128 q-rows): K/V staging+transpose per compute halves
//  - mask int32 -> permuted bf16 bias (pre-kernel); 4x8B loads/tile vs 16x4B
//  - softmax sum via MFMA ones-column (o_l) -> kills 16 shuffles/tile
//  - defer-max THR=8 (T13), wave-uniform __any -> rescale skipped ~31/32 tiles
//  - p_s handoff intra-wave: s_waitcnt lgkmcnt(0) instead of __syncthreads
//  - K/V global prefetch into regs (T14), consumed next iteration
//  - GEMM-style XOR swizzle on k_s/vt_s/p_s (byte ^= (row&7)<<4, both sides)
// GEMMs (split-bf16 3-pass MFMA, ~100us each) unchanged from R12.
// ---------------------------------------------------------------------------

typedef unsigned short u16;
typedef __attribute__((ext_vector_type(8))) short short8;
typedef __attribute__((ext_vector_type(8))) unsigned short u16x8;
typedef __attribute__((ext_vector_type(4))) unsigned short u16x4;
typedef __attribute__((ext_vector_type(4))) float floatx4;

__device__ u16 g_Bth[4][1024 * 1024];  // WqT,WkT,WvT,WoT hi bf16
__device__ u16 g_Btl[4][1024 * 1024];  // lo bf16
__device__ u16 g_Qh[8192 * 1024];      // bf16 Q projection
__device__ u16 g_Kh[8192 * 1024];      // bf16 K projection
__device__ u16 g_Vh[8192 * 1024];      // bf16 V projection
__device__ float g_O[8192 * 1024];     // fp32 attention output
__device__ u16 g_pbias[(size_t)4 * 2048 * 2048];  // permuted bf16 mask bias
__device__ int g_is_bf16;              // guard: input float dtype

__device__ __forceinline__ float bf2f(u16 u) {
  union { unsigned int i; float f; } v;
  v.i = ((unsigned int)u) << 16;
  return v.f;
}
__device__ __forceinline__ u16 f2bf(float f) {  // round-to-nearest-even
  union { float f; unsigned int i; } v;
  v.f = f;
  unsigned int r = v.i + 0x7fffu + ((v.i >> 16) & 1u);
  return (u16)(r >> 16);
}

// float-dtype guard (R6-validated): fp32 expected (g_is_bf16=0)
__global__ void detect_kernel(const u16* __restrict__ q) {
  if (threadIdx.x == 0) {
    int cnt = 0;
    for (int i = 0; i < 256; ++i) {
      const u16 v = q[i];
      const int e = (v >> 7) & 0xFF;
      cnt += ((e >= 100 && e <= 135) || ((v & 0x7FFF) == 0)) ? 1 : 0;
    }
    g_is_bf16 = (cnt >= 205) ? 1 : 0;
  }
}

__device__ __forceinline__ float load_in(const void* p, size_t i) {
  return g_is_bf16 ? bf2f(((const u16*)p)[i]) : ((const float*)p)[i];
}

// XOR swizzle for [rows][64 u16] (128B-row) LDS tiles: byte offset.
// Applied identically on write and read (rule: both-sides-or-neither).
__device__ __forceinline__ int swz128(int row, int cb) {
  return row * 128 + (cb ^ ((row & 7) << 4));
}
// XOR swizzle for [rows][32 u16] (64B-row) tiles (GEMM staging).
__device__ __forceinline__ int swz(int row, int cb) {
  return ((row << 6) + cb) ^ ((row & 7) << 4);
}

// ---------------------------------------------------------------------------
// mask int32 [B,1,S,S] -> permuted bf16 bias: 0 (keep) / -0.998e9 (mask).
// Layout: pbias[b][row][tile*64 + (c&15)*4 + (c>>4&3)] for col = tile*64+c,
// so attn thread (quad-row r, lanelo) reads its 4 ni values as one u16x4.
// ---------------------------------------------------------------------------
__global__ __launch_bounds__(256) void maskbias_kernel(const int* __restrict__ mask) {
  const size_t tid = (size_t)blockIdx.x * 256 + threadIdx.x;
  const size_t base = tid * 4;  // 4 cols per thread
  const int b = (int)(base >> 22);        // S*S = 2^22
  const size_t rem = base & 0x3FFFFFu;
  const int row = (int)(rem >> 11);       // S = 2^11
  const int c0 = (int)(rem & 2047);
  const int4 m = *(const int4*)(mask + base);
  const int tile = c0 >> 6;
  const int cl = c0 & 63;
  const int lan = cl & 15;   // c0 multiple of 4 -> lan in {0,4,8,12}
  const int ni = cl >> 4;
  u16* dst = g_pbias + ((size_t)b << 22) + ((size_t)row << 11) + tile * 64 + ni;
  const u16 NEG = 0xCE6E;  // bf16(-0.998e9)
  dst[(lan + 0) * 4] = m.x ? (u16)0 : NEG;
  dst[(lan + 1) * 4] = m.y ? (u16)0 : NEG;
  dst[(lan + 2) * 4] = m.z ? (u16)0 : NEG;
  dst[(lan + 3) * 4] = m.w ? (u16)0 : NEG;
}

// ---------------------------------------------------------------------------
// 1024x1024 transpose -> split bf16 hi/lo; out = g_Bth[wo], g_Btl[wo]
// ---------------------------------------------------------------------------
__global__ void wtrans_kernel(const void* __restrict__ in, int wo) {
  __shared__ float tile[32][33];
  const int tx = threadIdx.x, ty = threadIdx.y;
  const int n0 = blockIdx.x * 32, k0 = blockIdx.y * 32;
  tile[ty][tx] = load_in(in, (size_t)(k0 + ty) * 1024 + n0 + tx);
  __syncthreads();
  const float v = tile[tx][ty];
  const u16 h = f2bf(v);
  const u16 l = f2bf(v - bf2f(h));
  const size_t o = (size_t)(n0 + ty) * 1024 + k0 + tx;
  g_Bth[wo][o] = h;
  g_Btl[wo][o] = l;
}

// ---------------------------------------------------------------------------
// Split-bf16 MFMA GEMM (unchanged from R12, HW-verified):
// C[8192][1024] = A[8192][1024] x W + bias, W^T pre-split in g_Bth/g_Btl[bt].
// 128x128 tile, BK=32, 256 threads = 4 waves (2x2), 4x4 16x16x32 frags/wave.
// ---------------------------------------------------------------------------
__global__ __launch_bounds__(256) void gemm_mfma_kernel(
    const void* __restrict__ Aptr, int a_sel, int bt,
    const void* __restrict__ bias, float* __restrict__ Cptr, int c_sel) {
  constexpr int K = 1024, N = 1024;
  __shared__ __align__(16) u16 Ahs[128 * 32];
  __shared__ __align__(16) u16 Als[128 * 32];
  __shared__ __align__(16) u16 Bhs[128 * 32];
  __shared__ __align__(16) u16 Bls[128 * 32];

  const u16* Bth = g_Bth[bt];
  const u16* Btl = g_Btl[bt];
  u16* Ch = (c_sel == 0) ? g_Qh : (c_sel == 1) ? g_Kh : g_Vh;

  const int t = threadIdx.x;
  const int lane = t & 63;
  const int lanelo = lane & 15;
  const int quad = lane >> 4;
  const int wave = t >> 6;
  const int wr = wave >> 1, wc = wave & 1;

  const int bm = blockIdx.x * 128;
  const int bn = blockIdx.y * 128;

  const int sr = t >> 1;
  const int sc = (t & 1) * 16;

  const int bf = g_is_bf16;

  floatx4 acc[4][4];
#pragma unroll
  for (int i = 0; i < 4; ++i)
#pragma unroll
    for (int j = 0; j < 4; ++j) acc[i][j] = (floatx4)(0.f);

  for (int k0 = 0; k0 < K; k0 += 32) {
    float af[16];
    {
      const size_t ga = (size_t)(bm + sr) * K + k0 + sc;
      if (a_sel) {
#pragma unroll
        for (int i = 0; i < 4; ++i) {
          const float4 v = *(const float4*)(g_O + ga + i * 4);
          af[i * 4 + 0] = v.x; af[i * 4 + 1] = v.y;
          af[i * 4 + 2] = v.z; af[i * 4 + 3] = v.w;
        }
      } else if (!bf) {
#pragma unroll
        for (int i = 0; i < 4; ++i) {
          const float4 v = *(const float4*)((const float*)Aptr + ga + i * 4);
          af[i * 4 + 0] = v.x; af[i * 4 + 1] = v.y;
          af[i * 4 + 2] = v.z; af[i * 4 + 3] = v.w;
        }
      } else {
#pragma unroll
        for (int i = 0; i < 2; ++i) {
          const u16x8 v = *(const u16x8*)((const u16*)Aptr + ga + i * 8);
#pragma unroll
          for (int j = 0; j < 8; ++j) af[i * 8 + j] = bf2f(v[j]);
        }
      }
    }
    u16x8 bhv[2], blv[2];
    {
      const size_t gb = (size_t)(bn + sr) * K + k0 + sc;
      bhv[0] = *(const u16x8*)(Bth + gb);
      bhv[1] = *(const u16x8*)(Bth + gb + 8);
      blv[0] = *(const u16x8*)(Btl + gb);
      blv[1] = *(const u16x8*)(Btl + gb + 8);
    }

    __syncthreads();

    u16x8 ahv[2], alv[2];
#pragma unroll
    for (int i = 0; i < 2; ++i) {
#pragma unroll
      for (int j = 0; j < 8; ++j) {
        const float v = af[i * 8 + j];
        const u16 h = f2bf(v);
        ahv[i][j] = h;
        alv[i][j] = f2bf(v - bf2f(h));
      }
    }
#pragma unroll
    for (int i = 0; i < 2; ++i) {
      const int cb = sc * 2 + i * 16;
      const int o = swz(sr, cb) >> 1;
      *(u16x8*)&Ahs[o] = ahv[i];
      *(u16x8*)&Als[o] = alv[i];
      *(u16x8*)&Bhs[o] = bhv[i];
      *(u16x8*)&Bls[o] = blv[i];
    }

    __syncthreads();

    short8 a_h[4], a_l[4], b_h[4], b_l[4];
#pragma unroll
    for (int mi = 0; mi < 4; ++mi) {
      const int row = wr * 64 + mi * 16 + lanelo;
      const int o = swz(row, quad * 16) >> 1;
      a_h[mi] = *(const short8*)&Ahs[o];
      a_l[mi] = *(const short8*)&Als[o];
    }
#pragma unroll
    for (int ni = 0; ni < 4; ++ni) {
      const int row = wc * 64 + ni * 16 + lanelo;
      const int o = swz(row, quad * 16) >> 1;
      b_h[ni] = *(const short8*)&Bhs[o];
      b_l[ni] = *(const short8*)&Bls[o];
    }
#pragma unroll
    for (int mi = 0; mi < 4; ++mi)
#pragma unroll
      for (int ni = 0; ni < 4; ++ni) {
        acc[mi][ni] = __builtin_amdgcn_mfma_f32_16x16x32_bf16(
            a_h[mi], b_h[ni], acc[mi][ni], 0, 0, 0);
        acc[mi][ni] = __builtin_amdgcn_mfma_f32_16x16x32_bf16(
            a_h[mi], b_l[ni], acc[mi][ni], 0, 0, 0);
        acc[mi][ni] = __builtin_amdgcn_mfma_f32_16x16x32_bf16(
            a_l[mi], b_h[ni], acc[mi][ni], 0, 0, 0);
      }
  }

#pragma unroll
  for (int ni = 0; ni < 4; ++ni) {
    const int col = bn + wc * 64 + ni * 16 + lanelo;
    const float bv = bf ? bf2f(((const u16*)bias)[col])
                        : ((const float*)bias)[col];
#pragma unroll
    for (int mi = 0; mi < 4; ++mi) {
#pragma unroll
      for (int rg = 0; rg < 4; ++rg) {
        const int row = bm + wr * 64 + mi * 16 + quad * 4 + rg;
        const float v = acc[mi][ni][rg] + bv;
        if (c_sel == 3)
          Cptr[(size_t)row * N + col] = v;
        else
          Ch[(size_t)row * N + col] = f2bf(v);
      }
    }
  }
}

// ---------------------------------------------------------------------------
// MFMA flash attention R13: block = (128-q-tile, h, b), 512 threads (8 waves).
// Wave w owns q rows [w*16, w*16+16). Per 64-key tile:
//   S = Q K^T (Q frags hoisted in regs) -> *0.125 + pbias -> online softmax
//   (16-lane max reduce; defer-max THR=8; row-sum l via MFMA ones-column)
//   -> P bf16 via swizzled p_s (intra-wave: lgkmcnt not barrier) -> O += P V.
// k_s/vt_s/p_s: [rows][64 u16], XOR-swizzled both sides. K/V prefetched.
// ---------------------------------------------------------------------------
__global__ __launch_bounds__(512, 4) void attn_mfma_kernel() {
  constexpr int S = 2048, D = 1024, NT = S / 64;
  __shared__ __align__(16) u16 k_s[64 * 64];
  __shared__ __align__(16) u16 vt_s[64 * 64];   // vT[d][j]
  __shared__ __align__(16) u16 p_s[128 * 64];

  const int t = threadIdx.x;
  const int lane = t & 63;
  const int lanelo = lane & 15;
  const int quad = lane >> 4;
  const int wave = t >> 6;

  const int q0 = blockIdx.x * 128;
  const int h = blockIdx.y;
  const int b = blockIdx.z;
  const size_t bh = (size_t)b * S * D + (size_t)h * 64;

  // ---- Q fragments hoisted: A[m=lanelo][k=quad*8+u], invariant over kt ----
  short8 a_q[2];
#pragma unroll
  for (int kk = 0; kk < 2; ++kk)
    a_q[kk] = *(const short8*)(g_Qh + bh +
        (size_t)(q0 + wave * 16 + lanelo) * D + kk * 32 + quad * 8);

  // ones B-fragment (col 0 only) for row-sum accumulation
  short8 b_ones;
  {
    const short ov = (lanelo == 0) ? (short)0x3F80 : (short)0;
#pragma unroll
    for (int j = 0; j < 8; ++j) b_ones[j] = ov;
  }

  // staging: thread stages K/V row sj, u16 cols [scc, scc+8)
  const int sj = t & 63;
  const int scc = (t >> 6) * 8;

  const u16* Kbase = g_Kh + bh + (size_t)sj * D + scc;
  const u16* Vbase = g_Vh + bh + (size_t)sj * D + scc;
  u16x8 kreg = *(const u16x8*)(Kbase);
  u16x8 vreg = *(const u16x8*)(Vbase);

  floatx4 o_acc[4];
#pragma unroll
  for (int ni = 0; ni < 4; ++ni) o_acc[ni] = (floatx4)(0.f);
  floatx4 o_l = (floatx4)(0.f);  // row-sums (valid in lanelo==0 lanes)
  float m_r[4] = {-1e30f, -1e30f, -1e30f, -1e30f};

  const u16* pbrow = g_pbias + ((size_t)b << 22) +
                     ((size_t)(q0 + wave * 16 + quad * 4) << 11) + (lanelo << 2);

  for (int kt = 0; kt < NT; ++kt) {
    const int j0 = kt * 64;
    __syncthreads();  // prior k_s/vt_s/p_s reads complete

    // stage K (b128) + V transpose-on-store (swizzled)
    *(u16x8*)&k_s[swz128(sj, scc * 2) >> 1] = kreg;
#pragma unroll
    for (int u = 0; u < 8; ++u)
      vt_s[swz128(scc + u, sj * 2) >> 1] = vreg[u];
    __syncthreads();  // staging visible

    // prefetch next tile's K/V (latency hides under compute below)
    {
      const int ktn = (kt + 1 < NT) ? kt + 1 : kt;
      kreg = *(const u16x8*)(Kbase + (size_t)ktn * 64 * D);
      vreg = *(const u16x8*)(Vbase + (size_t)ktn * 64 * D);
    }
    // bias loads: 4 ni values per row r as one u16x4
    u16x4 bs[4];
#pragma unroll
    for (int r = 0; r < 4; ++r)
      bs[r] = *(const u16x4*)(pbrow + ((size_t)r << 11) + j0);

    // ---- QK^T ----
    floatx4 sacc[4];
#pragma unroll
    for (int ni = 0; ni < 4; ++ni) sacc[ni] = (floatx4)(0.f);
#pragma unroll
    for (int kk = 0; kk < 2; ++kk) {
#pragma unroll
      for (int ni = 0; ni < 4; ++ni) {
        const short8 bb = *(const short8*)
            &k_s[swz128(ni * 16 + lanelo, kk * 64 + quad * 16) >> 1];
        sacc[ni] = __builtin_amdgcn_mfma_f32_16x16x32_bf16(a_q[kk], bb, sacc[ni], 0, 0, 0);
      }
    }

    // scale + mask bias; element (ni,r): row=quad*4+r, col=ni*16+lanelo
    float sc[4][4];
#pragma unroll
    for (int r = 0; r < 4; ++r)
#pragma unroll
      for (int ni = 0; ni < 4; ++ni)
        sc[ni][r] = sacc[ni][r] * 0.125f + bf2f(bs[r][ni]);

    // row max across quad's 16 lanes
    float mloc[4];
#pragma unroll
    for (int r = 0; r < 4; ++r) {
      float m = fmaxf(fmaxf(sc[0][r], sc[1][r]), fmaxf(sc[2][r], sc[3][r]));
#pragma unroll
      for (int off = 1; off < 16; off <<= 1)
        m = fmaxf(m, __shfl_xor(m, off, 16));
      mloc[r] = m;
    }

    // defer-max (THR=8): rescale only if some row's max grew past m_r+8
    int grew = 0;
#pragma unroll
    for (int r = 0; r < 4; ++r) grew |= (mloc[r] > m_r[r] + 8.f) ? 1 : 0;
    if (__any(grew)) {
#pragma unroll
      for (int r = 0; r < 4; ++r) {
        const float m_new = fmaxf(m_r[r], mloc[r]);
        const float alpha = __expf(m_r[r] - m_new);
        m_r[r] = m_new;
#pragma unroll
        for (int ni = 0; ni < 4; ++ni) o_acc[ni][r] *= alpha;
        o_l[r] *= alpha;
      }
    }

    // P = exp(sc - m_r), bf16, swizzled scatter into p_s (intra-wave strip)
#pragma unroll
    for (int r = 0; r < 4; ++r) {
      const int prow = wave * 16 + quad * 4 + r;
#pragma unroll
      for (int ni = 0; ni < 4; ++ni) {
        const float p = __expf(sc[ni][r] - m_r[r]);
        p_s[swz128(prow, (ni * 16 + lanelo) * 2) >> 1] = f2bf(p);
      }
    }
    // producer and consumer of p_s rows [w*16,w*16+16) are the same wave:
    // wave-level LDS drain suffices, no workgroup barrier.
    asm volatile("s_waitcnt lgkmcnt(0)" ::: "memory");
    __builtin_amdgcn_sched_barrier(0);

    // ---- O += P V ; l += P . ones ----
#pragma unroll
    for (int kk = 0; kk < 2; ++kk) {
      const short8 a_p = *(const short8*)
          &p_s[swz128(wave * 16 + lanelo, kk * 64 + quad * 16) >> 1];
#pragma unroll
      for (int ni = 0; ni < 4; ++ni) {
        const short8 bb = *(const short8*)
            &vt_s[swz128(ni * 16 + lanelo, kk * 64 + quad * 16) >> 1];
        o_acc[ni] = __builtin_amdgcn_mfma_f32_16x16x32_bf16(a_p, bb, o_acc[ni], 0, 0, 0);
      }
      o_l = __builtin_amdgcn_mfma_f32_16x16x32_bf16(a_p, b_ones, o_l, 0, 0, 0);
    }
  }

  // epilogue: broadcast l from lanelo==0 lane of each quad, divide, store
#pragma unroll
  for (int r = 0; r < 4; ++r) {
    const float lsum = __shfl(o_l[r], lane & 48);
    const float inv = 1.f / lsum;
    const int row = q0 + wave * 16 + quad * 4 + r;
#pragma unroll
    for (int ni = 0; ni < 4; ++ni)
      g_O[bh + (size_t)row * D + ni * 16 + lanelo] = o_acc[ni][r] * inv;
  }
}

// ---------------------------------------------------------------------------
extern "C" void kernel_launch(void* const* d_in, const int* in_sizes, int n_in,
                              void* d_out, int out_size, void* d_ws, size_t ws_size,
                              hipStream_t stream) {
  const void* query = d_in[0];
  const void* key   = d_in[1];
  const void* value = d_in[2];
  const int* mask   = (const int*)d_in[3];
  const void* Wq = d_in[4];
  const void* bq = d_in[5];
  const void* Wk = d_in[6];
  const void* bk = d_in[7];
  const void* Wv = d_in[8];
  const void* bv = d_in[9];
  const void* Wo = d_in[10];
  const void* bo = d_in[11];

  detect_kernel<<<1, 64, 0, stream>>>((const u16*)query);

  maskbias_kernel<<<16384, 256, 0, stream>>>(mask);  // 4*2048*2048/4/256

  dim3 tb(32, 32), tg(32, 32);
  wtrans_kernel<<<tg, tb, 0, stream>>>(Wq, 0);
  wtrans_kernel<<<tg, tb, 0, stream>>>(Wk, 1);
  wtrans_kernel<<<tg, tb, 0, stream>>>(Wv, 2);
  wtrans_kernel<<<tg, tb, 0, stream>>>(Wo, 3);

  dim3 gg(64, 8);  // 8192/128 x 1024/128
  gemm_mfma_kernel<<<gg, 256, 0, stream>>>(query, 0, 0, bq, nullptr, 0);
  gemm_mfma_kernel<<<gg, 256, 0, stream>>>(key,   0, 1, bk, nullptr, 1);
  gemm_mfma_kernel<<<gg, 256, 0, stream>>>(value, 0, 2, bv, nullptr, 2);

  attn_mfma_kernel<<<dim3(16, 16, 4), 512, 0, stream>>>();

  gemm_mfma_kernel<<<gg, 256, 0, stream>>>(nullptr, 1, 3, bo, (float*)d_out, 3);
}